// Round 11
// baseline (1109.331 us; speedup 1.0000x reference)
//
#include <hip/hip_runtime.h>
#include <math.h>
#include <float.h>

#define T_SEQ  2048
#define DMODEL 512
#define NHEAD  8
#define DHEAD  64
#define FDIM   2048
#define NLAYER 4
#define NB     2
#define MROWS  (NB*T_SEQ)   // 4096

typedef _Float16 f16x8 __attribute__((ext_vector_type(8)));
typedef float    f32x4 __attribute__((ext_vector_type(4)));

// async 16B global -> LDS (wave-uniform LDS base, lane x 16B dest)
__device__ __forceinline__ void async16(const _Float16* g, _Float16* l) {
    __builtin_amdgcn_global_load_lds(
        (const __attribute__((address_space(1))) unsigned int*)g,
        (__attribute__((address_space(3))) unsigned int*)l, 16, 0, 0);
}

// ---------------------------------------------------------------------------
// fp32 vector GEMM — embedding only (K=128)
// ---------------------------------------------------------------------------
template<int BN, int EPI>
__global__ __launch_bounds__(256) void gemm_k(
    const float* __restrict__ A, const float* __restrict__ W,
    const float* __restrict__ bias, const float* __restrict__ pos,
    float* __restrict__ C, int M, int N, int K)
{
    constexpr int BM = 128;
    constexpr int BK = 32;
    constexpr int MN = BN / 16;
    __shared__ float As[BK][BM + 4];
    __shared__ float Ws[BK][BN + 4];
    const int tid = threadIdx.x;
    const int n0 = blockIdx.x * BN;
    const int m0 = blockIdx.y * BM;
    const int tx = tid & 15;
    const int ty = tid >> 4;

    float acc[8][MN];
    #pragma unroll
    for (int i = 0; i < 8; ++i)
        #pragma unroll
        for (int j = 0; j < MN; ++j) acc[i][j] = 0.f;

    for (int k0 = 0; k0 < K; k0 += BK) {
        #pragma unroll
        for (int it = 0; it < 4; ++it) {
            int qq = tid + 256 * it;
            int m = qq >> 3, kq = qq & 7;
            float4 v4 = *(const float4*)(A + (size_t)(m0 + m) * K + k0 + kq * 4);
            As[kq*4+0][m] = v4.x; As[kq*4+1][m] = v4.y;
            As[kq*4+2][m] = v4.z; As[kq*4+3][m] = v4.w;
        }
        #pragma unroll
        for (int it = 0; it < BN/32; ++it) {
            int qq = tid + 256 * it;
            int n = qq >> 3, kq = qq & 7;
            float4 v4 = *(const float4*)(W + (size_t)(n0 + n) * K + k0 + kq * 4);
            Ws[kq*4+0][n] = v4.x; Ws[kq*4+1][n] = v4.y;
            Ws[kq*4+2][n] = v4.z; Ws[kq*4+3][n] = v4.w;
        }
        __syncthreads();
        for (int kk = 0; kk < BK; ++kk) {
            float a[8], b[MN];
            float4 a0 = *(const float4*)&As[kk][ty*8];
            float4 a1 = *(const float4*)&As[kk][ty*8+4];
            a[0]=a0.x; a[1]=a0.y; a[2]=a0.z; a[3]=a0.w;
            a[4]=a1.x; a[5]=a1.y; a[6]=a1.z; a[7]=a1.w;
            float4 b0 = *(const float4*)&Ws[kk][tx*4];
            b[0]=b0.x; b[1]=b0.y; b[2]=b0.z; b[3]=b0.w;
            if constexpr (MN == 8) {
                float4 b1 = *(const float4*)&Ws[kk][64 + tx*4];
                b[4]=b1.x; b[5]=b1.y; b[6]=b1.z; b[7]=b1.w;
            }
            #pragma unroll
            for (int i = 0; i < 8; ++i)
                #pragma unroll
                for (int j = 0; j < MN; ++j)
                    acc[i][j] = fmaf(a[i], b[j], acc[i][j]);
        }
        __syncthreads();
    }

    #pragma unroll
    for (int i = 0; i < 8; ++i) {
        int m = m0 + ty*8 + i;
        #pragma unroll
        for (int jb = 0; jb < MN/4; ++jb) {
            int nn = n0 + jb*64 + tx*4;
            float4 r;
            r.x = acc[i][jb*4+0] + bias[nn+0];
            r.y = acc[i][jb*4+1] + bias[nn+1];
            r.z = acc[i][jb*4+2] + bias[nn+2];
            r.w = acc[i][jb*4+3] + bias[nn+3];
            if constexpr (EPI == 1) {
                const float* pp = pos + (size_t)(m & (T_SEQ-1)) * DMODEL + nn;
                r.x += pp[0]; r.y += pp[1]; r.z += pp[2]; r.w += pp[3];
            }
            *(float4*)(C + (size_t)m * N + nn) = r;
        }
    }
}

// ---------------------------------------------------------------------------
// f16-split MFMA GEMM: C = (1/1024)·A'[M,K]·W'[N,K]^T + bias
// v7: W never touches LDS. K-block-major W planes mean each lane's MFMA
// B-fragment is a CONTIGUOUS 16B in global: load it straight into VGPRs
// (wave = 4 x 256B coalesced segments; W panels XCD-L2-pinned per R7).
// The K-loop was LDS-read-throughput bound (8 ds_read_b128 : 12 MFMA per
// wave-step = 96 : 58 cyc/CU) - halving LDS reads attacks that directly,
// plus removes W staging and frees 16-32KB LDS.
// A stays reg-staged from ROW-MAJOR activations (R9; R10's k-block-major
// activations regressed: producer epilogues became scattered 16B stores).
// WDB (NJ<=2, MW<=4): register-double-buffered W, 2-step-unrolled loop with
// static buffer indices (rule #20). QKV (MW=6 VGPR cap) and fc1 (NJ=4):
// same-step W loads to stay under VGPR caps; TLP hides the L2 latency.
// Retained: 512-thr/8-wave blocks (R9), A-dbuf + 1 barrier/K-step (R6),
// n-panel-fastest XCD pinning (R7), k-block-major W (R8).
// ASRC: 0 = dual-plane A; 1 = single-plane A (exact spikes; AsL elided)
// EPI:  0 = fp32; 2 = spike->fp32; 3 = spike->f16 plane (x16)
// LAYOUT: 0 = [M,N]; 2 = fused QKV (q,k f16 planes head layout; v fp32)
// MW: min waves/EU for launch_bounds (QKV: 6 -> 3 blocks/CU; others 4)
// ---------------------------------------------------------------------------
template<int BM, int BN, int ASRC, int EPI, int LAYOUT, int MW>
__global__ __launch_bounds__(512, MW) void mgemm_k(
    const _Float16* __restrict__ AH, const _Float16* __restrict__ AL,
    const _Float16* __restrict__ WH, const _Float16* __restrict__ WL,
    const float* __restrict__ bias,
    float* __restrict__ O0, float* __restrict__ O1, float* __restrict__ O2,
    float* __restrict__ O3, float* __restrict__ O4,
    int M, int N, int K)
{
    constexpr int WMv = (BM == 128) ? 4 : ((BN == 128) ? 2 : 4);
    constexpr int WNv = 8 / WMv;
    constexpr int MI  = BM / WMv / 16;
    constexpr int NJ  = BN / WNv / 16;
    __shared__ _Float16 AsH[2][4][BM][8];
    __shared__ _Float16 AsL[(ASRC == 0) ? 2 : 1][(ASRC == 0) ? 4 : 1][(ASRC == 0) ? BM : 1][8];

    const int tid = threadIdx.x;
    // n-panel-fastest decomposition: bid%npan -> XCD-pinned W panel
    const int npan = N / BN;
    const int bid  = blockIdx.x;
    const int n0 = (bid % npan) * BN;
    const int m0 = (bid / npan) * BM;
    const int wv = tid >> 6, lane = tid & 63;
    const int mw = (wv / WNv) * (BM / WMv);
    const int nw = (wv % WNv) * (BN / WNv);
    const int fr = lane & 15;
    const int kb = lane >> 4;

    // A register prefetch holders (one f16x8 slot per thread per plane)
    f16x8 pa0, pal0;

    auto gloadA = [&](int k0) {
        if constexpr (BM == 128) {
            const int r_ = tid >> 2, kb_ = tid & 3;
            pa0 = *(const f16x8*)(AH + (size_t)(m0 + r_) * K + k0 + kb_*8);
            if constexpr (ASRC == 0)
                pal0 = *(const f16x8*)(AL + (size_t)(m0 + r_) * K + k0 + kb_*8);
        } else {
            const int slot = tid & 255, r_ = slot >> 2, kb_ = slot & 3;
            if constexpr (ASRC == 0) {
                const _Float16* src = (tid < 256) ? AH : AL;
                pa0 = *(const f16x8*)(src + (size_t)(m0 + r_) * K + k0 + kb_*8);
            } else {
                if (tid < 256)
                    pa0 = *(const f16x8*)(AH + (size_t)(m0 + r_) * K + k0 + kb_*8);
            }
        }
    };
    auto swriteA = [&](int buf) {
        if constexpr (BM == 128) {
            *(f16x8*)&AsH[buf][tid & 3][tid >> 2][0] = pa0;
            if constexpr (ASRC == 0)
                *(f16x8*)&AsL[buf][tid & 3][tid >> 2][0] = pal0;
        } else {
            const int slot = tid & 255, r_ = slot >> 2, kb_ = slot & 3;
            if constexpr (ASRC == 0) {
                _Float16* d = (tid < 256) ? &AsH[buf][kb_][r_][0] : &AsL[buf][kb_][r_][0];
                *(f16x8*)d = pa0;
            } else {
                if (tid < 256) *(f16x8*)&AsH[buf][kb_][r_][0] = pa0;
            }
        }
    };

    // W fragments direct from global (k-block-major planes): lane's
    // fragment = contiguous 16B at ((k0>>3)+kb)*N + n0+nw+j*16+fr
    auto loadW = [&](int k0, f16x8 (&dH)[NJ], f16x8 (&dL)[NJ]) {
        const size_t kk = ((size_t)(k0 >> 3) + kb) * N;
        #pragma unroll
        for (int j = 0; j < NJ; ++j) {
            const size_t off = (kk + n0 + nw + j*16 + fr) * 8;
            dH[j] = *(const f16x8*)(WH + off);
            dL[j] = *(const f16x8*)(WL + off);
        }
    };

    f32x4 acc[MI][NJ];
    #pragma unroll
    for (int i = 0; i < MI; ++i)
        #pragma unroll
        for (int j = 0; j < NJ; ++j) acc[i][j] = (f32x4)(0.f);

    auto mfma_step = [&](int buf, f16x8 (&bH)[NJ], f16x8 (&bL)[NJ]) {
        f16x8 aH[MI], aL[MI];
        #pragma unroll
        for (int i = 0; i < MI; ++i) {
            aH[i] = *(const f16x8*)&AsH[buf][kb][mw + i*16 + fr][0];
            if constexpr (ASRC == 0)
                aL[i] = *(const f16x8*)&AsL[buf][kb][mw + i*16 + fr][0];
        }
        #pragma unroll
        for (int i = 0; i < MI; ++i)
            #pragma unroll
            for (int j = 0; j < NJ; ++j) {
                acc[i][j] = __builtin_amdgcn_mfma_f32_16x16x32_f16(aH[i], bH[j], acc[i][j], 0, 0, 0);
                acc[i][j] = __builtin_amdgcn_mfma_f32_16x16x32_f16(aH[i], bL[j], acc[i][j], 0, 0, 0);
                if constexpr (ASRC == 0)
                    acc[i][j] = __builtin_amdgcn_mfma_f32_16x16x32_f16(aL[i], bH[j], acc[i][j], 0, 0, 0);
            }
    };

    const int NT = K >> 5;
    constexpr bool WDB = (NJ <= 2) && (MW <= 4);   // reg-dbuf W where VGPR allows
    f16x8 bAH[NJ], bAL[NJ];

    if constexpr (WDB) {
        f16x8 bBH[NJ], bBL[NJ];
        loadW(0, bAH, bAL);
        gloadA(0); swriteA(0);
        __syncthreads();
        for (int t = 0; t < NT; t += 2) {
            if (t + 1 < NT) { loadW((t+1) << 5, bBH, bBL); gloadA((t+1) << 5); }
            mfma_step(0, bAH, bAL);
            if (t + 1 < NT) { swriteA(1); __syncthreads(); }
            if (t + 2 < NT) { loadW((t+2) << 5, bAH, bAL); gloadA((t+2) << 5); }
            if (t + 1 < NT) mfma_step(1, bBH, bBL);
            if (t + 2 < NT) { swriteA(0); __syncthreads(); }
        }
    } else {
        int cur = 0;
        gloadA(0); swriteA(0);
        __syncthreads();
        for (int t = 0; t < NT; ++t) {
            const bool more = (t + 1 < NT);
            if (more) gloadA((t + 1) << 5);
            loadW(t << 5, bAH, bAL);
            mfma_step(cur, bAH, bAL);
            if (more) {
                swriteA(cur ^ 1);
                __syncthreads();
                cur ^= 1;
            }
        }
    }

    const int qq = lane >> 4;
    #pragma unroll
    for (int j = 0; j < NJ; ++j) {
        int n = n0 + nw + j*16 + fr;
        float bv = bias[n];
        #pragma unroll
        for (int i = 0; i < MI; ++i) {
            #pragma unroll
            for (int r = 0; r < 4; ++r) {
                int m = m0 + mw + i*16 + qq*4 + r;
                float val = acc[i][j][r] * (1.f/1024.f) + bv;
                if constexpr (EPI == 2) val = val > 0.5f ? 1.f : 0.f;
                if constexpr (EPI == 3) {
                    ((_Float16*)O0)[(size_t)m * N + n] = (val > 0.5f) ? (_Float16)16.f : (_Float16)0.f;
                } else if constexpr (LAYOUT == 0) {
                    O0[(size_t)m * N + n] = val;
                } else {
                    int b_ = m >> 11, t_ = m & (T_SEQ-1);
                    if (n < 512) {
                        size_t hl = (((size_t)(b_*NHEAD + (n>>6))*T_SEQ + t_) << 6) + (n & 63);
                        float s16 = 16.f * val;
                        _Float16 hh = (_Float16)s16;
                        ((_Float16*)O0)[hl] = hh;
                        ((_Float16*)O1)[hl] = (_Float16)(s16 - (float)hh);
                    } else if (n < 1024) {
                        int nn = n - 512;
                        size_t hl = (((size_t)(b_*NHEAD + (nn>>6))*T_SEQ + t_) << 6) + (nn & 63);
                        float s16 = 16.f * val;
                        _Float16 hh = (_Float16)s16;
                        ((_Float16*)O2)[hl] = hh;
                        ((_Float16*)O3)[hl] = (_Float16)(s16 - (float)hh);
                    } else {
                        int nn = n - 1024;
                        O4[(((size_t)(b_*NHEAD + (nn>>6))*T_SEQ + t_) << 6) + (nn & 63)] = val;
                    }
                }
            }
        }
    }
}

// ---------------------------------------------------------------------------
// h-split (embedding output -> x16 planes)
// ---------------------------------------------------------------------------
__global__ __launch_bounds__(256) void cvtw_k(
    const float* __restrict__ w, _Float16* __restrict__ H, _Float16* __restrict__ L,
    int n, float scale)
{
    int i = blockIdx.x * 256 + threadIdx.x;
    if (i < n) {
        float s = scale * w[i];
        _Float16 h = (_Float16)s;
        H[i] = h;
        L[i] = (_Float16)(s - (float)h);
    }
}

// all of one layer's weight conversions fused (x64 split), one launch.
// Writes k-block-major planes WT[(k>>3)*N + n][8] (R8).
__global__ __launch_bounds__(256) void cvtlayer_k(
    const float* __restrict__ wq, const float* __restrict__ wk, const float* __restrict__ wv,
    const float* __restrict__ bq, const float* __restrict__ bk, const float* __restrict__ bv,
    const float* __restrict__ wo, const float* __restrict__ f1w, const float* __restrict__ f2w,
    _Float16* __restrict__ WcatH, _Float16* __restrict__ WcatL, float* __restrict__ bcat,
    _Float16* __restrict__ WoH, _Float16* __restrict__ WoL,
    _Float16* __restrict__ W1H, _Float16* __restrict__ W1L,
    _Float16* __restrict__ W2H, _Float16* __restrict__ W2L)
{
    int i = blockIdx.x * 256 + threadIdx.x;
    float w;
    _Float16 *H, *L;
    int off;
    if (i < 786432) {
        // Wcat: N=1536 (q|k|v rows), K=512
        int j = i;
        int kbq = j / 12288;             // N*8 = 12288
        int rem = j - kbq * 12288;
        int n = rem >> 3;
        int k = kbq * 8 + (j & 7);
        int sm = n >> 9, nn = n & 511;
        w = (sm == 0 ? wq : (sm == 1 ? wk : wv))[nn * 512 + k];
        H = WcatH; L = WcatL; off = j;
    } else if (i < 1048576) {
        // Wo: N=512, K=512 (N*8 = 4096)
        int j = i - 786432;
        int kbq = j >> 12;
        int n = (j >> 3) & 511;
        int k = (kbq << 3) | (j & 7);
        w = wo[n * 512 + k];
        H = WoH; L = WoL; off = j;
    } else if (i < 2097152) {
        // W1: N=2048, K=512 (N*8 = 16384)
        int j = i - 1048576;
        int kbq = j >> 14;
        int n = (j >> 3) & 2047;
        int k = (kbq << 3) | (j & 7);
        w = f1w[n * 512 + k];
        H = W1H; L = W1L; off = j;
    } else if (i < 3145728) {
        // W2: N=512, K=2048 (N*8 = 4096)
        int j = i - 2097152;
        int kbq = j >> 12;
        int n = (j >> 3) & 511;
        int k = (kbq << 3) | (j & 7);
        w = f2w[n * 2048 + k];
        H = W2H; L = W2L; off = j;
    } else if (i < 3145728 + 1536) {
        int j = i - 3145728;
        int src = j >> 9, o = j & 511;
        bcat[j] = (src == 0 ? bq : (src == 1 ? bk : bv))[o];
        return;
    } else return;
    float s = 64.f * w;
    _Float16 h = (_Float16)s;
    H[off] = h;
    L[off] = (_Float16)(s - (float)h);
}

// ---------------------------------------------------------------------------
// Fused sparse attention v9 — 512 thr / 64 q-rows, 512 blocks = 2/CU exactly;
// ss[64][132] padded; sort-16 CE as explicit min/max; Q in registers;
// async K staging; __expf softmax. Row-major outputs (R9).
// ---------------------------------------------------------------------------
__global__ __launch_bounds__(512, 4) void attn_k(
    const _Float16* __restrict__ qH, const _Float16* __restrict__ qL,
    const _Float16* __restrict__ kH, const _Float16* __restrict__ kL,
    const float* __restrict__ v,
    _Float16* __restrict__ outH, _Float16* __restrict__ outL)
{
    // ksH [128*64] @0 (16384) | ksL @16384 | ss[64][132] f32 @32768 (33792)
    // -> total 66560; wrow/irow alias ss
    __shared__ unsigned char lds[66560];
    _Float16* ksH = (_Float16*)(lds);
    _Float16* ksL = (_Float16*)(lds + 16384);
    float    (*ss)[132] = (float(*)[132])(lds + 32768);
    float*   wrow       = (float*)(lds + 32768);
    int*     irow       = (int*)(lds + 32768 + 8448);

    const int tid = threadIdx.x;
    const int bh  = blockIdx.y;
    const int t0  = blockIdx.x * 64;
    const _Float16* qHb = qH + ((size_t)bh * T_SEQ + t0) * DHEAD;
    const _Float16* qLb = qL + ((size_t)bh * T_SEQ + t0) * DHEAD;
    const _Float16* kHb = kH + (size_t)bh * T_SEQ * DHEAD;
    const _Float16* kLb = kL + (size_t)bh * T_SEQ * DHEAD;
    const float*    vb  = v  + (size_t)bh * T_SEQ * DHEAD;

    unsigned kreg[32];
    #pragma unroll
    for (int i = 0; i < 32; ++i) kreg[i] = 0u;

    const int wv = tid >> 6, lane = tid & 63;
    const int fr = lane & 15, q4 = lane >> 4;
    const int mh  = (wv >> 2) * 32;      // q-row half owned by this wave
    const int c0w = (wv & 3) * 32;       // col strip owned by this wave
    const int srow = tid >> 3;           // 0..63
    const int ssub = tid & 7;

    // Q fragments in registers: loop-invariant across all K tiles.
    // [ks][mi]: row = mh + mi*16 + fr; doff = ks*32 + q4*8
    f16x8 qaH[2][2], qaL[2][2];
    #pragma unroll
    for (int ks = 0; ks < 2; ++ks) {
        const int doff = ks*32 + q4*8;
        qaH[ks][0] = *(const f16x8*)(qHb + (mh + fr)*DHEAD + doff);
        qaH[ks][1] = *(const f16x8*)(qHb + (mh + 16 + fr)*DHEAD + doff);
        qaL[ks][0] = *(const f16x8*)(qLb + (mh + fr)*DHEAD + doff);
        qaL[ks][1] = *(const f16x8*)(qLb + (mh + 16 + fr)*DHEAD + doff);
    }

    // async stage of one K tile: 8 waves x 16 rows -> 2 instrs/plane/wave
    auto stage = [&](int jt) {
        const int j0 = jt * 128;
        #pragma unroll
        for (int i = 0; i < 2; ++i) {
            const int r0 = wv*16 + i*8;                 // wave-uniform
            const int cc = r0 + (lane >> 3);
            const int ch = (lane & 7) ^ (cc & 7);       // swizzled source chunk
            const size_t goff = (size_t)(j0 + cc) * DHEAD + ch*8;
            async16(kHb + goff, ksH + r0*64);
            async16(kLb + goff, ksL + r0*64);
        }
    };

    stage(0);
    __syncthreads();                     // ks(0) ready (drains vmcnt)

    for (int jt = 0; jt < 16; ++jt) {
        const int j0 = jt * 128;

        // QK^T: 2 m-frags x 2 n-frags x 2 k-steps x 3 split passes
        f32x4 acc[2][2];
        acc[0][0] = (f32x4)(0.f); acc[0][1] = (f32x4)(0.f);
        acc[1][0] = (f32x4)(0.f); acc[1][1] = (f32x4)(0.f);
        #pragma unroll
        for (int ks = 0; ks < 2; ++ks) {
            const int chq  = ks*4 + q4;                 // chunk index of doff
            #pragma unroll
            for (int nj = 0; nj < 2; ++nj) {
                const int cc = c0w + nj*16 + fr;
                const int sl = cc*64 + (chq ^ (cc & 7))*8;
                f16x8 bHf = *(const f16x8*)&ksH[sl];
                f16x8 bLf = *(const f16x8*)&ksL[sl];
                acc[0][nj] = __builtin_amdgcn_mfma_f32_16x16x32_f16(qaH[ks][0], bHf, acc[0][nj], 0, 0, 0);
                acc[0][nj] = __builtin_amdgcn_mfma_f32_16x16x32_f16(qaH[ks][0], bLf, acc[0][nj], 0, 0, 0);
                acc[0][nj] = __builtin_amdgcn_mfma_f32_16x16x32_f16(qaL[ks][0], bHf, acc[0][nj], 0, 0, 0);
                acc[1][nj] = __builtin_amdgcn_mfma_f32_16x16x32_f16(qaH[ks][1], bHf, acc[1][nj], 0, 0, 0);
                acc[1][nj] = __builtin_amdgcn_mfma_f32_16x16x32_f16(qaH[ks][1], bLf, acc[1][nj], 0, 0, 0);
                acc[1][nj] = __builtin_amdgcn_mfma_f32_16x16x32_f16(qaL[ks][1], bHf, acc[1][nj], 0, 0, 0);
            }
        }
        // scores to LDS (row = mh + mi*16 + q4*4 + r, col = c0w + nj*16 + fr)
        #pragma unroll
        for (int mi = 0; mi < 2; ++mi)
            #pragma unroll
            for (int nj = 0; nj < 2; ++nj)
                #pragma unroll
                for (int r = 0; r < 4; ++r)
                    ss[mh + mi*16 + q4*4 + r][c0w + nj*16 + fr] = acc[mi][nj][r] * (1.f/2048.f);
        __syncthreads();                 // C: ss visible; all ks reads done

        if (jt < 15) stage(jt + 1);      // async; hides under select

        // branch-free select: 16 candidates / thread, u32 packed keys
        float4 c4[4];
        {
            const float* ssr = &ss[srow][0] + ssub*4;
            #pragma unroll
            for (int g = 0; g < 4; ++g) c4[g] = *(const float4*)(ssr + g*32);
        }
        unsigned cand[16];
        #pragma unroll
        for (int g = 0; g < 4; ++g) {
            float vg[4] = {c4[g].x, c4[g].y, c4[g].z, c4[g].w};
            #pragma unroll
            for (int r = 0; r < 4; ++r) {
                unsigned u = __float_as_uint(vg[r]);
                u ^= (unsigned)((int)u >> 31) | 0x80000000u;
                int col = ssub*4 + g*32 + r;
                cand[g*4+r] = (u & 0xFFFFF800u) | (unsigned)(2047 - (j0 + col));
            }
        }
        // bitonic sort-16 descending; CE as explicit min/max (v_min/max_u32)
        #pragma unroll
        for (int k2 = 2; k2 <= 16; k2 <<= 1) {
            #pragma unroll
            for (int j2 = k2 >> 1; j2 > 0; j2 >>= 1) {
                #pragma unroll
                for (int i2 = 0; i2 < 16; ++i2) {
                    int l2 = i2 ^ j2;
                    if (l2 > i2) {
                        unsigned a = cand[i2], b = cand[l2];
                        unsigned mn = a < b ? a : b;
                        unsigned mx = a < b ? b : a;
                        if ((i2 & k2) == 0) { cand[i2] = mx; cand[l2] = mn; }
                        else                { cand[i2] = mn; cand[l2] = mx; }
                    }
                }
            }
        }
        #pragma unroll
        for (int j2 = 0; j2 < 16; ++j2) {
            unsigned b = cand[15 - j2];
            if (kreg[16 + j2] < b) kreg[16 + j2] = b;
        }
        #pragma unroll
        for (int st = 16; st >= 1; st >>= 1) {
            #pragma unroll
            for (int i2 = 0; i2 < 32; ++i2) {
                if ((i2 & st) == 0) {
                    unsigned lo = kreg[i2], hi = kreg[i2 | st];
                    kreg[i2]      = lo < hi ? hi : lo;
                    kreg[i2 | st] = lo < hi ? lo : hi;
                }
            }
        }
        __syncthreads();                 // A: ks(t+1) ready; ss reads done
    }

    // merge 8 per-sub lists (lane^1,2,4)
    #pragma unroll
    for (int s = 1; s <= 4; s <<= 1) {
        #pragma unroll
        for (int i = 0; i < 16; ++i) {
            unsigned pa = (unsigned)__shfl_xor((int)kreg[31-i], s, 64);
            unsigned pb = (unsigned)__shfl_xor((int)kreg[i],    s, 64);
            if (pa > kreg[i])    kreg[i]    = pa;
            if (pb > kreg[31-i]) kreg[31-i] = pb;
        }
        #pragma unroll
        for (int st = 16; st >= 1; st >>= 1) {
            #pragma unroll
            for (int i2 = 0; i2 < 32; ++i2) {
                if ((i2 & st) == 0) {
                    unsigned lo = kreg[i2], hi = kreg[i2 | st];
                    kreg[i2]      = lo < hi ? hi : lo;
                    kreg[i2 | st] = lo < hi ? lo : hi;
                }
            }
        }
    }

    // softmax over kept 32
    if (ssub == 0) {
        float w[32];
        #pragma unroll
        for (int i = 0; i < 32; ++i) {
            unsigned um = kreg[i] & 0xFFFFF800u;
            unsigned ub = (um & 0x80000000u) ? (um ^ 0x80000000u) : ~um;
            w[i] = __uint_as_float(ub);
        }
        float m = w[0];
        float s = 0.f;
        #pragma unroll
        for (int i = 0; i < 32; ++i) { w[i] = __expf(w[i] - m); s += w[i]; }
        float inv = 1.f / s;
        #pragma unroll
        for (int i = 0; i < 32; ++i) {
            wrow[srow*33 + i] = w[i] * inv;
            irow[srow*33 + i] = 2047 - (int)(kreg[i] & 0x7FFu);
        }
    }
    __syncthreads();

    // AV: wave per row-group, lane = head dim; 4 partial accumulators
    const int wid = tid >> 6, lane2 = tid & 63;
    const int b = bh >> 3, h = bh & 7;
    for (int rr = wid; rr < 64; rr += 8) {
        float a0 = 0.f, a1 = 0.f, a2 = 0.f, a3 = 0.f;
        #pragma unroll
        for (int i = 0; i < 8; ++i) {
            a0 = fmaf(wrow[rr*33 + i],      vb[(size_t)irow[rr*33 + i]      * DHEAD + lane2], a0);
            a1 = fmaf(wrow[rr*33 + 8 + i],  vb[(size_t)irow[rr*33 + 8 + i]  * DHEAD + lane2], a1);
            a2 = fmaf(wrow[rr*33 + 16 + i], vb[(size_t)irow[rr*33 + 16 + i] * DHEAD + lane2], a2);
            a3 = fmaf(wrow[rr*33 + 24 + i], vb[(size_t)irow[rr*33 + 24 + i] * DHEAD + lane2], a3);
        }
        float accv = (a0 + a1) + (a2 + a3);
        size_t oi = ((size_t)(b * T_SEQ + t0 + rr)) * DMODEL + h * DHEAD + lane2;
        float s16 = 16.f * accv;
        _Float16 hh = (_Float16)s16;
        outH[oi] = hh;
        outL[oi] = (_Float16)(s16 - (float)hh);
    }
}

// ---------------------------------------------------------------------------
// LayerNorm (+residual); also emits x16 f16 hi/lo planes of the output
// ---------------------------------------------------------------------------
__global__ __launch_bounds__(256) void ln_k(
    const float* __restrict__ x, const float* __restrict__ res,
    const float* __restrict__ g, const float* __restrict__ bb,
    float* __restrict__ out, _Float16* __restrict__ oH, _Float16* __restrict__ oL)
{
    __shared__ float red[8];
    const int row = blockIdx.x;
    const int tid = threadIdx.x;
    const float* xr = x + (size_t)row * DMODEL;
    float v0 = xr[tid], v1 = xr[tid + 256];
    if (res) {
        const float* rr = res + (size_t)row * DMODEL;
        v0 += rr[tid]; v1 += rr[tid + 256];
    }
    float s = v0 + v1;
    #pragma unroll
    for (int o = 1; o < 64; o <<= 1) s += __shfl_xor(s, o);
    const int wid = tid >> 6, lane = tid & 63;
    if (lane == 0) red[wid] = s;
    __syncthreads();
    float mean = (red[0] + red[1] + red[2] + red[3]) * (1.f / DMODEL);
    float d0 = v0 - mean, d1 = v1 - mean;
    float qs = d0*d0 + d1*d1;
    #pragma unroll
    for (int o = 1; o < 64; o <<= 1) qs += __shfl_xor(qs, o);
    if (lane == 0) red[4 + wid] = qs;
    __syncthreads();
    float var = (red[4] + red[5] + red[6] + red[7]) * (1.f / DMODEL);
    float rs = rsqrtf(var + 1e-5f);
    float o0 = d0 * rs * g[tid]       + bb[tid];
    float o1 = d1 * rs * g[tid + 256] + bb[tid + 256];
    size_t base = (size_t)row * DMODEL;
    out[base + tid]       = o0;
    out[base + tid + 256] = o1;
    float s0 = 16.f * o0, s1 = 16.f * o1;
    _Float16 h0 = (_Float16)s0, h1 = (_Float16)s1;
    oH[base + tid]       = h0;
    oH[base + tid + 256] = h1;
    oL[base + tid]       = (_Float16)(s0 - (float)h0);
    oL[base + tid + 256] = (_Float16)(s1 - (float)h1);
}

// ---------------------------------------------------------------------------
__global__ __launch_bounds__(256) void pool_k(
    const float* __restrict__ h, float* __restrict__ part)
{
    const int chunk = blockIdx.x & 15;
    const int idx = (blockIdx.x >> 4) * 256 + threadIdx.x;
    const int b = idx >> 9, d = idx & 511;
    const float* p = h + ((size_t)b * T_SEQ + chunk * 128) * DMODEL + d;
    float s = 0.f;
    for (int t = 0; t < 128; ++t) s += p[(size_t)t * DMODEL];
    part[chunk * 1024 + idx] = s;
}

__global__ __launch_bounds__(256) void poolsum_k(
    const float* __restrict__ part, float* __restrict__ pooled)
{
    int idx = blockIdx.x * 256 + threadIdx.x;
    float s = 0.f;
    #pragma unroll
    for (int c = 0; c < 16; ++c) s += part[c * 1024 + idx];
    pooled[idx] = s * (1.f / T_SEQ);
}

__global__ __launch_bounds__(256) void cls_k(
    const float* __restrict__ pooled, const float* __restrict__ w,
    const float* __restrict__ bias, float* __restrict__ out)
{
    const int wid = threadIdx.x >> 6, lane = threadIdx.x & 63;
    const int oi = blockIdx.x * 4 + wid;
    const int b = oi >> 8, o = oi & 255;
    const float* pr = pooled + b * DMODEL;
    const float* wr = w + (size_t)o * DMODEL;
    float s = 0.f;
    for (int d = lane; d < DMODEL; d += 64) s = fmaf(pr[d], wr[d], s);
    #pragma unroll
    for (int off = 1; off < 64; off <<= 1) s += __shfl_xor(s, off);
    if (lane == 0) out[oi] = s + bias[o];
}

// ---------------------------------------------------------------------------
extern "C" void kernel_launch(void* const* d_in, const int* in_sizes, int n_in,
                              void* d_out, int out_size, void* d_ws, size_t ws_size,
                              hipStream_t stream)
{
    const float* x     = (const float*)d_in[0];
    const float* emb_w = (const float*)d_in[1];
    const float* emb_b = (const float*)d_in[2];
    const float* pos   = (const float*)d_in[3];
    const float* wq    = (const float*)d_in[4];
    const float* bq    = (const float*)d_in[5];
    const float* wk    = (const float*)d_in[6];
    const float* bk    = (const float*)d_in[7];
    const float* wv    = (const float*)d_in[8];
    const float* bv    = (const float*)d_in[9];
    const float* wo    = (const float*)d_in[10];
    const float* bo    = (const float*)d_in[11];
    const float* ln1g  = (const float*)d_in[12];
    const float* ln1b  = (const float*)d_in[13];
    const float* fc1w  = (const float*)d_in[14];
    const float* fc1b  = (const float*)d_in[15];
    const float* fc2w  = (const float*)d_in[16];
    const float* fc2b  = (const float*)d_in[17];
    const float* ln2g  = (const float*)d_in[18];
    const float* ln2b  = (const float*)d_in[19];
    const float* fng   = (const float*)d_in[20];
    const float* fnb   = (const float*)d_in[21];
    const float* clsw  = (const float*)d_in[22];
    const float* clsb  = (const float*)d_in[23];

    float* ws = (float*)d_ws;
    const size_t SZ  = (size_t)MROWS * DMODEL;   // 2,097,152 floats
    const size_t HP  = SZ / 2;
    float*     h     = ws;
    float*     t1    = ws + 1*SZ;
    _Float16*  hH    = (_Float16*)(ws + 2*SZ);
    _Float16*  hL    = (_Float16*)(ws + 2*SZ + HP);
    _Float16*  aoH   = (_Float16*)(ws + 3*SZ);
    _Float16*  aoL   = (_Float16*)(ws + 3*SZ + HP);
    _Float16*  qbH   = (_Float16*)(ws + 4*SZ);
    _Float16*  qbL   = (_Float16*)(ws + 4*SZ + HP);
    _Float16*  kbH   = (_Float16*)(ws + 5*SZ);
    _Float16*  kbL   = (_Float16*)(ws + 5*SZ + HP);
    float*     vbuf  = ws + 6*SZ;
    _Float16*  WcatH = (_Float16*)(ws + 7*SZ);
    _Float16*  WcatL = (_Float16*)(ws + 7*SZ + 393216);
    _Float16*  WoH   = (_Float16*)(ws + 7*SZ + 786432);
    _Float16*  WoL   = (_Float16*)(ws + 7*SZ + 917504);
    _Float16*  W1H   = (_Float16*)(ws + 7*SZ + 1048576);
    _Float16*  W1L   = (_Float16*)(ws + 7*SZ + 1572864);
    _Float16*  W2H   = (_Float16*)(ws + 7*SZ + 2097152);
    _Float16*  W2L   = (_Float16*)(ws + 7*SZ + 2621440);
    float*     bcat  = ws + 7*SZ + 3145728;
    float*     pooled= ws + 7*SZ + 3145728 + 1536;
    float*     part  = ws + 7*SZ + 3145728 + 1536 + 1024;
    _Float16*  hid   = (_Float16*)(ws + 4*SZ);   // aliases q/k planes (dead then)
    const size_t needed = (7*SZ + 3145728 + 1536 + 1024 + 16384) * sizeof(float);
    if (ws_size < needed) return;

    dim3 blk(256);

    gemm_k<64,1><<<dim3(DMODEL/64, MROWS/128), blk, 0, stream>>>(
        x, emb_w, emb_b, pos, h, MROWS, DMODEL, 128);
    cvtw_k<<<dim3((int)(SZ/256)), blk, 0, stream>>>(h, hH, hL, (int)SZ, 16.f);

    for (int l = 0; l < NLAYER; ++l) {
        const float* wq_l = wq + (size_t)l*DMODEL*DMODEL;
        const float* bq_l = bq + (size_t)l*DMODEL;
        const float* wk_l = wk + (size_t)l*DMODEL*DMODEL;
        const float* bk_l = bk + (size_t)l*DMODEL;
        const float* wv_l = wv + (size_t)l*DMODEL*DMODEL;
        const float* bv_l = bv + (size_t)l*DMODEL;
        const float* wo_l = wo + (size_t)l*DMODEL*DMODEL;
        const float* bo_l = bo + (size_t)l*DMODEL;
        const float* f1w_l = fc1w + (size_t)l*FDIM*DMODEL;
        const float* f1b_l = fc1b + (size_t)l*FDIM;
        const float* f2w_l = fc2w + (size_t)l*DMODEL*FDIM;
        const float* f2b_l = fc2b + (size_t)l*DMODEL;

        // all weight conversions for this layer in one launch (k-block-major)
        cvtlayer_k<<<dim3(12294), blk, 0, stream>>>(
            wq_l, wk_l, wv_l, bq_l, bk_l, bv_l, wo_l, f1w_l, f2w_l,
            WcatH, WcatL, bcat, WoH, WoL, W1H, W1L, W2H, W2L);

        // fused QKV: 768 blocks x 512 thr = 3 blocks/CU x 8 waves = 24 w/CU
        mgemm_k<64,128,0,0,2,6><<<dim3(768), dim3(512), 0, stream>>>(
            hH, hL, WcatH, WcatL, bcat,
            (float*)qbH, (float*)qbL, (float*)kbH, (float*)kbL, vbuf,
            MROWS, 1536, DMODEL);

        attn_k<<<dim3(T_SEQ/64, NB*NHEAD), dim3(512), 0, stream>>>(
            qbH, qbL, kbH, kbL, vbuf, aoH, aoL);

        // o-proj + spike: 512 blocks x 512 thr = 2/CU x 8 waves = 16 w/CU
        mgemm_k<64,64,0,2,0,4><<<dim3(512), dim3(512), 0, stream>>>(
            aoH, aoL, WoH, WoL, bo_l, t1, nullptr, nullptr, nullptr, nullptr,
            MROWS, DMODEL, DMODEL);
        ln_k<<<dim3(MROWS), blk, 0, stream>>>(h, t1, ln1g + (size_t)l*DMODEL,
                                              ln1b + (size_t)l*DMODEL, h, hH, hL);

        // fc1: 512 blocks x 512 thr; fc2: 512 blocks x 512 thr
        mgemm_k<128,128,0,3,0,4><<<dim3(512), dim3(512), 0, stream>>>(
            hH, hL, W1H, W1L, f1b_l, (float*)hid, nullptr, nullptr, nullptr, nullptr,
            MROWS, FDIM, DMODEL);
        mgemm_k<64,64,1,2,0,4><<<dim3(512), dim3(512), 0, stream>>>(
            hid, nullptr, W2H, W2L, f2b_l, t1, nullptr, nullptr, nullptr, nullptr,
            MROWS, DMODEL, FDIM);
        ln_k<<<dim3(MROWS), blk, 0, stream>>>(h, t1, ln2g + (size_t)l*DMODEL,
                                              ln2b + (size_t)l*DMODEL, h, hH, hL);
    }

    ln_k<<<dim3(MROWS), blk, 0, stream>>>(h, nullptr, fng, fnb, h, hH, hL);
    pool_k<<<dim3(64), blk, 0, stream>>>(h, part);
    poolsum_k<<<dim3(4), blk, 0, stream>>>(part, pooled);
    cls_k<<<dim3(128), blk, 0, stream>>>(pooled, clsw, clsb, (float*)d_out);
}

// Round 14
// 1040.359 us; speedup vs baseline: 1.0663x; 1.0663x over previous
//
#include <hip/hip_runtime.h>
#include <math.h>
#include <float.h>

#define T_SEQ  2048
#define DMODEL 512
#define NHEAD  8
#define DHEAD  64
#define FDIM   2048
#define NLAYER 4
#define NB     2
#define MROWS  (NB*T_SEQ)   // 4096

typedef _Float16 f16x8 __attribute__((ext_vector_type(8)));
typedef float    f32x4 __attribute__((ext_vector_type(4)));

// async 16B global -> LDS (wave-uniform LDS base, lane x 16B dest)
__device__ __forceinline__ void async16(const _Float16* g, _Float16* l) {
    __builtin_amdgcn_global_load_lds(
        (const __attribute__((address_space(1))) unsigned int*)g,
        (__attribute__((address_space(3))) unsigned int*)l, 16, 0, 0);
}

// ---------------------------------------------------------------------------
// Embedding GEMM (K=128) with fused h-split epilogue (replaces old
// gemm_k + cvtw_k: saves one full 8MB-read/8MB-write pass + a launch).
// R12 bug fixed: W staging needs BN/32 = 2 iterations (n = 0..63), the
// single-iteration version left Ws rows 32..63 stale.
// ---------------------------------------------------------------------------
__global__ __launch_bounds__(256) void gemm2_k(
    const float* __restrict__ A, const float* __restrict__ W,
    const float* __restrict__ bias, const float* __restrict__ pos,
    float* __restrict__ C, _Float16* __restrict__ OH, _Float16* __restrict__ OL,
    int M, int N, int K)
{
    constexpr int BM = 128;
    constexpr int BN = 64;
    constexpr int BK = 32;
    constexpr int MN = BN / 16;   // 4
    __shared__ float As[BK][BM + 4];
    __shared__ float Ws[BK][BN + 4];
    const int tid = threadIdx.x;
    const int n0 = blockIdx.x * BN;
    const int m0 = blockIdx.y * BM;
    const int tx = tid & 15;
    const int ty = tid >> 4;

    float acc[8][MN];
    #pragma unroll
    for (int i = 0; i < 8; ++i)
        #pragma unroll
        for (int j = 0; j < MN; ++j) acc[i][j] = 0.f;

    for (int k0 = 0; k0 < K; k0 += BK) {
        #pragma unroll
        for (int it = 0; it < 4; ++it) {
            int qq = tid + 256 * it;
            int m = qq >> 3, kq = qq & 7;
            float4 v4 = *(const float4*)(A + (size_t)(m0 + m) * K + k0 + kq * 4);
            As[kq*4+0][m] = v4.x; As[kq*4+1][m] = v4.y;
            As[kq*4+2][m] = v4.z; As[kq*4+3][m] = v4.w;
        }
        #pragma unroll
        for (int it = 0; it < BN/32; ++it) {   // 2 iterations: n = 0..63
            int qq = tid + 256 * it;
            int n = qq >> 3, kq = qq & 7;
            float4 v4 = *(const float4*)(W + (size_t)(n0 + n) * K + k0 + kq * 4);
            Ws[kq*4+0][n] = v4.x; Ws[kq*4+1][n] = v4.y;
            Ws[kq*4+2][n] = v4.z; Ws[kq*4+3][n] = v4.w;
        }
        __syncthreads();
        for (int kk = 0; kk < BK; ++kk) {
            float a[8], b[MN];
            float4 a0 = *(const float4*)&As[kk][ty*8];
            float4 a1 = *(const float4*)&As[kk][ty*8+4];
            a[0]=a0.x; a[1]=a0.y; a[2]=a0.z; a[3]=a0.w;
            a[4]=a1.x; a[5]=a1.y; a[6]=a1.z; a[7]=a1.w;
            float4 b0 = *(const float4*)&Ws[kk][tx*4];
            b[0]=b0.x; b[1]=b0.y; b[2]=b0.z; b[3]=b0.w;
            #pragma unroll
            for (int i = 0; i < 8; ++i)
                #pragma unroll
                for (int j = 0; j < MN; ++j)
                    acc[i][j] = fmaf(a[i], b[j], acc[i][j]);
        }
        __syncthreads();
    }

    #pragma unroll
    for (int i = 0; i < 8; ++i) {
        int m = m0 + ty*8 + i;
        int nn = n0 + tx*4;
        float4 r;
        r.x = acc[i][0] + bias[nn+0];
        r.y = acc[i][1] + bias[nn+1];
        r.z = acc[i][2] + bias[nn+2];
        r.w = acc[i][3] + bias[nn+3];
        const float* pp = pos + (size_t)(m & (T_SEQ-1)) * DMODEL + nn;
        r.x += pp[0]; r.y += pp[1]; r.z += pp[2]; r.w += pp[3];
        *(float4*)(C + (size_t)m * N + nn) = r;
        // fused h-split (x16): identical bytes to the old cvtw_k pass
        float rv[4] = {r.x, r.y, r.z, r.w};
        _Float16 hv[4], lv[4];
        #pragma unroll
        for (int q = 0; q < 4; ++q) {
            float s16 = 16.f * rv[q];
            _Float16 hh = (_Float16)s16;
            hv[q] = hh;
            lv[q] = (_Float16)(s16 - (float)hh);
        }
        size_t base = (size_t)m * N + nn;
        *(float2*)(OH + base) = *(const float2*)hv;   // 4 halfs = 8B
        *(float2*)(OL + base) = *(const float2*)lv;
    }
}

// ---------------------------------------------------------------------------
// f16-split MFMA GEMM (R9 best config): 512-thread blocks, async-W staging
// from k-block-major planes, reg-staged A from row-major activations,
// dbuf + 1 barrier/K-step, n-panel-fastest XCD pinning.
// ASRC: 0 = dual-plane A; 1 = single-plane A (exact spikes; AsL elided)
// EPI:  0 = fp32; 2 = spike->fp32; 3 = spike->f16 plane (x16)
// LAYOUT: 0 = [M,N]; 2 = fused QKV (q,k f16 planes head layout; v fp32)
// MW: min waves/EU for launch_bounds (QKV: 6 -> 3 blocks/CU; others 4)
// ---------------------------------------------------------------------------
template<int BM, int BN, int ASRC, int EPI, int LAYOUT, int MW>
__global__ __launch_bounds__(512, MW) void mgemm_k(
    const _Float16* __restrict__ AH, const _Float16* __restrict__ AL,
    const _Float16* __restrict__ WH, const _Float16* __restrict__ WL,
    const float* __restrict__ bias,
    float* __restrict__ O0, float* __restrict__ O1, float* __restrict__ O2,
    float* __restrict__ O3, float* __restrict__ O4,
    int M, int N, int K)
{
    constexpr int WMv = (BM == 128) ? 4 : ((BN == 128) ? 2 : 4);
    constexpr int WNv = 8 / WMv;
    constexpr int MI  = BM / WMv / 16;
    constexpr int NJ  = BN / WNv / 16;
    __shared__ _Float16 AsH[2][4][BM][8];
    __shared__ _Float16 AsL[(ASRC == 0) ? 2 : 1][(ASRC == 0) ? 4 : 1][(ASRC == 0) ? BM : 1][8];
    __shared__ _Float16 WsH[2][4][BN][8];
    __shared__ _Float16 WsL[2][4][BN][8];

    const int tid = threadIdx.x;
    const int npan = N / BN;
    const int bid  = blockIdx.x;
    const int n0 = (bid % npan) * BN;
    const int m0 = (bid / npan) * BM;
    const int wv = tid >> 6, lane = tid & 63;
    const int mw = (wv / WNv) * (BM / WMv);
    const int nw = (wv % WNv) * (BN / WNv);
    const int fr = lane & 15;
    const int kb = lane >> 4;

    f16x8 pa0, pal0;

    auto stageW = [&](int k0, int buf) {
        const int kb_ = wv & 3;
        const _Float16* WP = (wv >= 4) ? WL : WH;
        _Float16* db = (wv >= 4) ? &WsL[buf][kb_][0][0] : &WsH[buf][kb_][0][0];
        const size_t sb = ((size_t)((k0 >> 3) + kb_) * N + n0);
        async16(WP + (sb + lane) * 8, db);
        if constexpr (BN == 128)
            async16(WP + (sb + 64 + lane) * 8, db + 64 * 8);
    };
    auto gloadA = [&](int k0) {
        if constexpr (BM == 128) {
            const int r_ = tid >> 2, kb_ = tid & 3;
            pa0 = *(const f16x8*)(AH + (size_t)(m0 + r_) * K + k0 + kb_*8);
            if constexpr (ASRC == 0)
                pal0 = *(const f16x8*)(AL + (size_t)(m0 + r_) * K + k0 + kb_*8);
        } else {
            const int slot = tid & 255, r_ = slot >> 2, kb_ = slot & 3;
            if constexpr (ASRC == 0) {
                const _Float16* src = (tid < 256) ? AH : AL;
                pa0 = *(const f16x8*)(src + (size_t)(m0 + r_) * K + k0 + kb_*8);
            } else {
                if (tid < 256)
                    pa0 = *(const f16x8*)(AH + (size_t)(m0 + r_) * K + k0 + kb_*8);
            }
        }
    };
    auto swriteA = [&](int buf) {
        if constexpr (BM == 128) {
            *(f16x8*)&AsH[buf][tid & 3][tid >> 2][0] = pa0;
            if constexpr (ASRC == 0)
                *(f16x8*)&AsL[buf][tid & 3][tid >> 2][0] = pal0;
        } else {
            const int slot = tid & 255, r_ = slot >> 2, kb_ = slot & 3;
            if constexpr (ASRC == 0) {
                _Float16* d = (tid < 256) ? &AsH[buf][kb_][r_][0] : &AsL[buf][kb_][r_][0];
                *(f16x8*)d = pa0;
            } else {
                if (tid < 256) *(f16x8*)&AsH[buf][kb_][r_][0] = pa0;
            }
        }
    };

    f32x4 acc[MI][NJ];
    #pragma unroll
    for (int i = 0; i < MI; ++i)
        #pragma unroll
        for (int j = 0; j < NJ; ++j) acc[i][j] = (f32x4)(0.f);

    const int NT = K >> 5;
    int cur = 0;
    stageW(0, 0);
    gloadA(0);
    swriteA(0);
    __syncthreads();

    for (int t = 0; t < NT; ++t) {
        const bool more = (t + 1 < NT);
        if (more) {
            stageW((t + 1) << 5, cur ^ 1);
            gloadA((t + 1) << 5);
        }

        f16x8 aH[MI], aL[MI], bH[NJ], bL[NJ];
        #pragma unroll
        for (int i = 0; i < MI; ++i) {
            aH[i] = *(const f16x8*)&AsH[cur][kb][mw + i*16 + fr][0];
            if constexpr (ASRC == 0) aL[i] = *(const f16x8*)&AsL[cur][kb][mw + i*16 + fr][0];
        }
        #pragma unroll
        for (int j = 0; j < NJ; ++j) {
            bH[j] = *(const f16x8*)&WsH[cur][kb][nw + j*16 + fr][0];
            bL[j] = *(const f16x8*)&WsL[cur][kb][nw + j*16 + fr][0];
        }
        #pragma unroll
        for (int i = 0; i < MI; ++i)
            #pragma unroll
            for (int j = 0; j < NJ; ++j) {
                acc[i][j] = __builtin_amdgcn_mfma_f32_16x16x32_f16(aH[i], bH[j], acc[i][j], 0, 0, 0);
                acc[i][j] = __builtin_amdgcn_mfma_f32_16x16x32_f16(aH[i], bL[j], acc[i][j], 0, 0, 0);
                if constexpr (ASRC == 0)
                    acc[i][j] = __builtin_amdgcn_mfma_f32_16x16x32_f16(aL[i], bH[j], acc[i][j], 0, 0, 0);
            }
        if (more) {
            swriteA(cur ^ 1);
            __syncthreads();
            cur ^= 1;
        }
    }

    const int qq = lane >> 4;
    #pragma unroll
    for (int j = 0; j < NJ; ++j) {
        int n = n0 + nw + j*16 + fr;
        float bv = bias[n];
        #pragma unroll
        for (int i = 0; i < MI; ++i) {
            #pragma unroll
            for (int r = 0; r < 4; ++r) {
                int m = m0 + mw + i*16 + qq*4 + r;
                float val = acc[i][j][r] * (1.f/1024.f) + bv;
                if constexpr (EPI == 2) val = val > 0.5f ? 1.f : 0.f;
                if constexpr (EPI == 3) {
                    ((_Float16*)O0)[(size_t)m * N + n] = (val > 0.5f) ? (_Float16)16.f : (_Float16)0.f;
                } else if constexpr (LAYOUT == 0) {
                    O0[(size_t)m * N + n] = val;
                } else {
                    int b_ = m >> 11, t_ = m & (T_SEQ-1);
                    if (n < 512) {
                        size_t hl = (((size_t)(b_*NHEAD + (n>>6))*T_SEQ + t_) << 6) + (n & 63);
                        float s16 = 16.f * val;
                        _Float16 hh = (_Float16)s16;
                        ((_Float16*)O0)[hl] = hh;
                        ((_Float16*)O1)[hl] = (_Float16)(s16 - (float)hh);
                    } else if (n < 1024) {
                        int nn = n - 512;
                        size_t hl = (((size_t)(b_*NHEAD + (nn>>6))*T_SEQ + t_) << 6) + (nn & 63);
                        float s16 = 16.f * val;
                        _Float16 hh = (_Float16)s16;
                        ((_Float16*)O2)[hl] = hh;
                        ((_Float16*)O3)[hl] = (_Float16)(s16 - (float)hh);
                    } else {
                        int nn = n - 1024;
                        O4[(((size_t)(b_*NHEAD + (nn>>6))*T_SEQ + t_) << 6) + (nn & 63)] = val;
                    }
                }
            }
        }
    }
}

// all of one layer's weight conversions fused (x64 split), one launch.
// Writes k-block-major planes WT[(k>>3)*N + n][8] (R8).
__global__ __launch_bounds__(256) void cvtlayer_k(
    const float* __restrict__ wq, const float* __restrict__ wk, const float* __restrict__ wv,
    const float* __restrict__ bq, const float* __restrict__ bk, const float* __restrict__ bv,
    const float* __restrict__ wo, const float* __restrict__ f1w, const float* __restrict__ f2w,
    _Float16* __restrict__ WcatH, _Float16* __restrict__ WcatL, float* __restrict__ bcat,
    _Float16* __restrict__ WoH, _Float16* __restrict__ WoL,
    _Float16* __restrict__ W1H, _Float16* __restrict__ W1L,
    _Float16* __restrict__ W2H, _Float16* __restrict__ W2L)
{
    int i = blockIdx.x * 256 + threadIdx.x;
    float w;
    _Float16 *H, *L;
    int off;
    if (i < 786432) {
        int j = i;
        int kbq = j / 12288;
        int rem = j - kbq * 12288;
        int n = rem >> 3;
        int k = kbq * 8 + (j & 7);
        int sm = n >> 9, nn = n & 511;
        w = (sm == 0 ? wq : (sm == 1 ? wk : wv))[nn * 512 + k];
        H = WcatH; L = WcatL; off = j;
    } else if (i < 1048576) {
        int j = i - 786432;
        int kbq = j >> 12;
        int n = (j >> 3) & 511;
        int k = (kbq << 3) | (j & 7);
        w = wo[n * 512 + k];
        H = WoH; L = WoL; off = j;
    } else if (i < 2097152) {
        int j = i - 1048576;
        int kbq = j >> 14;
        int n = (j >> 3) & 2047;
        int k = (kbq << 3) | (j & 7);
        w = f1w[n * 512 + k];
        H = W1H; L = W1L; off = j;
    } else if (i < 3145728) {
        int j = i - 2097152;
        int kbq = j >> 12;
        int n = (j >> 3) & 511;
        int k = (kbq << 3) | (j & 7);
        w = f2w[n * 2048 + k];
        H = W2H; L = W2L; off = j;
    } else if (i < 3145728 + 1536) {
        int j = i - 3145728;
        int src = j >> 9, o = j & 511;
        bcat[j] = (src == 0 ? bq : (src == 1 ? bk : bv))[o];
        return;
    } else return;
    float s = 64.f * w;
    _Float16 h = (_Float16)s;
    H[off] = h;
    L[off] = (_Float16)(s - (float)h);
}

// ---------------------------------------------------------------------------
// Fused sparse attention v9 — 512 thr / 64 q-rows, 512 blocks = 2/CU exactly;
// ss[64][132] padded; sort-16 CE as explicit min/max; Q in registers;
// async K staging; __expf softmax. Row-major outputs.
// ---------------------------------------------------------------------------
__global__ __launch_bounds__(512, 4) void attn_k(
    const _Float16* __restrict__ qH, const _Float16* __restrict__ qL,
    const _Float16* __restrict__ kH, const _Float16* __restrict__ kL,
    const float* __restrict__ v,
    _Float16* __restrict__ outH, _Float16* __restrict__ outL)
{
    __shared__ unsigned char lds[66560];
    _Float16* ksH = (_Float16*)(lds);
    _Float16* ksL = (_Float16*)(lds + 16384);
    float    (*ss)[132] = (float(*)[132])(lds + 32768);
    float*   wrow       = (float*)(lds + 32768);
    int*     irow       = (int*)(lds + 32768 + 8448);

    const int tid = threadIdx.x;
    const int bh  = blockIdx.y;
    const int t0  = blockIdx.x * 64;
    const _Float16* qHb = qH + ((size_t)bh * T_SEQ + t0) * DHEAD;
    const _Float16* qLb = qL + ((size_t)bh * T_SEQ + t0) * DHEAD;
    const _Float16* kHb = kH + (size_t)bh * T_SEQ * DHEAD;
    const _Float16* kLb = kL + (size_t)bh * T_SEQ * DHEAD;
    const float*    vb  = v  + (size_t)bh * T_SEQ * DHEAD;

    unsigned kreg[32];
    #pragma unroll
    for (int i = 0; i < 32; ++i) kreg[i] = 0u;

    const int wv = tid >> 6, lane = tid & 63;
    const int fr = lane & 15, q4 = lane >> 4;
    const int mh  = (wv >> 2) * 32;
    const int c0w = (wv & 3) * 32;
    const int srow = tid >> 3;
    const int ssub = tid & 7;

    f16x8 qaH[2][2], qaL[2][2];
    #pragma unroll
    for (int ks = 0; ks < 2; ++ks) {
        const int doff = ks*32 + q4*8;
        qaH[ks][0] = *(const f16x8*)(qHb + (mh + fr)*DHEAD + doff);
        qaH[ks][1] = *(const f16x8*)(qHb + (mh + 16 + fr)*DHEAD + doff);
        qaL[ks][0] = *(const f16x8*)(qLb + (mh + fr)*DHEAD + doff);
        qaL[ks][1] = *(const f16x8*)(qLb + (mh + 16 + fr)*DHEAD + doff);
    }

    auto stage = [&](int jt) {
        const int j0 = jt * 128;
        #pragma unroll
        for (int i = 0; i < 2; ++i) {
            const int r0 = wv*16 + i*8;
            const int cc = r0 + (lane >> 3);
            const int ch = (lane & 7) ^ (cc & 7);
            const size_t goff = (size_t)(j0 + cc) * DHEAD + ch*8;
            async16(kHb + goff, ksH + r0*64);
            async16(kLb + goff, ksL + r0*64);
        }
    };

    stage(0);
    __syncthreads();

    for (int jt = 0; jt < 16; ++jt) {
        const int j0 = jt * 128;

        f32x4 acc[2][2];
        acc[0][0] = (f32x4)(0.f); acc[0][1] = (f32x4)(0.f);
        acc[1][0] = (f32x4)(0.f); acc[1][1] = (f32x4)(0.f);
        #pragma unroll
        for (int ks = 0; ks < 2; ++ks) {
            const int chq  = ks*4 + q4;
            #pragma unroll
            for (int nj = 0; nj < 2; ++nj) {
                const int cc = c0w + nj*16 + fr;
                const int sl = cc*64 + (chq ^ (cc & 7))*8;
                f16x8 bHf = *(const f16x8*)&ksH[sl];
                f16x8 bLf = *(const f16x8*)&ksL[sl];
                acc[0][nj] = __builtin_amdgcn_mfma_f32_16x16x32_f16(qaH[ks][0], bHf, acc[0][nj], 0, 0, 0);
                acc[0][nj] = __builtin_amdgcn_mfma_f32_16x16x32_f16(qaH[ks][0], bLf, acc[0][nj], 0, 0, 0);
                acc[0][nj] = __builtin_amdgcn_mfma_f32_16x16x32_f16(qaL[ks][0], bHf, acc[0][nj], 0, 0, 0);
                acc[1][nj] = __builtin_amdgcn_mfma_f32_16x16x32_f16(qaH[ks][1], bHf, acc[1][nj], 0, 0, 0);
                acc[1][nj] = __builtin_amdgcn_mfma_f32_16x16x32_f16(qaH[ks][1], bLf, acc[1][nj], 0, 0, 0);
                acc[1][nj] = __builtin_amdgcn_mfma_f32_16x16x32_f16(qaL[ks][1], bHf, acc[1][nj], 0, 0, 0);
            }
        }
        #pragma unroll
        for (int mi = 0; mi < 2; ++mi)
            #pragma unroll
            for (int nj = 0; nj < 2; ++nj)
                #pragma unroll
                for (int r = 0; r < 4; ++r)
                    ss[mh + mi*16 + q4*4 + r][c0w + nj*16 + fr] = acc[mi][nj][r] * (1.f/2048.f);
        __syncthreads();

        if (jt < 15) stage(jt + 1);

        float4 c4[4];
        {
            const float* ssr = &ss[srow][0] + ssub*4;
            #pragma unroll
            for (int g = 0; g < 4; ++g) c4[g] = *(const float4*)(ssr + g*32);
        }
        unsigned cand[16];
        #pragma unroll
        for (int g = 0; g < 4; ++g) {
            float vg[4] = {c4[g].x, c4[g].y, c4[g].z, c4[g].w};
            #pragma unroll
            for (int r = 0; r < 4; ++r) {
                unsigned u = __float_as_uint(vg[r]);
                u ^= (unsigned)((int)u >> 31) | 0x80000000u;
                int col = ssub*4 + g*32 + r;
                cand[g*4+r] = (u & 0xFFFFF800u) | (unsigned)(2047 - (j0 + col));
            }
        }
        #pragma unroll
        for (int k2 = 2; k2 <= 16; k2 <<= 1) {
            #pragma unroll
            for (int j2 = k2 >> 1; j2 > 0; j2 >>= 1) {
                #pragma unroll
                for (int i2 = 0; i2 < 16; ++i2) {
                    int l2 = i2 ^ j2;
                    if (l2 > i2) {
                        unsigned a = cand[i2], b = cand[l2];
                        unsigned mn = a < b ? a : b;
                        unsigned mx = a < b ? b : a;
                        if ((i2 & k2) == 0) { cand[i2] = mx; cand[l2] = mn; }
                        else                { cand[i2] = mn; cand[l2] = mx; }
                    }
                }
            }
        }
        #pragma unroll
        for (int j2 = 0; j2 < 16; ++j2) {
            unsigned b = cand[15 - j2];
            if (kreg[16 + j2] < b) kreg[16 + j2] = b;
        }
        #pragma unroll
        for (int st = 16; st >= 1; st >>= 1) {
            #pragma unroll
            for (int i2 = 0; i2 < 32; ++i2) {
                if ((i2 & st) == 0) {
                    unsigned lo = kreg[i2], hi = kreg[i2 | st];
                    kreg[i2]      = lo < hi ? hi : lo;
                    kreg[i2 | st] = lo < hi ? lo : hi;
                }
            }
        }
        __syncthreads();
    }

    #pragma unroll
    for (int s = 1; s <= 4; s <<= 1) {
        #pragma unroll
        for (int i = 0; i < 16; ++i) {
            unsigned pa = (unsigned)__shfl_xor((int)kreg[31-i], s, 64);
            unsigned pb = (unsigned)__shfl_xor((int)kreg[i],    s, 64);
            if (pa > kreg[i])    kreg[i]    = pa;
            if (pb > kreg[31-i]) kreg[31-i] = pb;
        }
        #pragma unroll
        for (int st = 16; st >= 1; st >>= 1) {
            #pragma unroll
            for (int i2 = 0; i2 < 32; ++i2) {
                if ((i2 & st) == 0) {
                    unsigned lo = kreg[i2], hi = kreg[i2 | st];
                    kreg[i2]      = lo < hi ? hi : lo;
                    kreg[i2 | st] = lo < hi ? lo : hi;
                }
            }
        }
    }

    if (ssub == 0) {
        float w[32];
        #pragma unroll
        for (int i = 0; i < 32; ++i) {
            unsigned um = kreg[i] & 0xFFFFF800u;
            unsigned ub = (um & 0x80000000u) ? (um ^ 0x80000000u) : ~um;
            w[i] = __uint_as_float(ub);
        }
        float m = w[0];
        float s = 0.f;
        #pragma unroll
        for (int i = 0; i < 32; ++i) { w[i] = __expf(w[i] - m); s += w[i]; }
        float inv = 1.f / s;
        #pragma unroll
        for (int i = 0; i < 32; ++i) {
            wrow[srow*33 + i] = w[i] * inv;
            irow[srow*33 + i] = 2047 - (int)(kreg[i] & 0x7FFu);
        }
    }
    __syncthreads();

    const int wid = tid >> 6, lane2 = tid & 63;
    const int b = bh >> 3, h = bh & 7;
    for (int rr = wid; rr < 64; rr += 8) {
        float a0 = 0.f, a1 = 0.f, a2 = 0.f, a3 = 0.f;
        #pragma unroll
        for (int i = 0; i < 8; ++i) {
            a0 = fmaf(wrow[rr*33 + i],      vb[(size_t)irow[rr*33 + i]      * DHEAD + lane2], a0);
            a1 = fmaf(wrow[rr*33 + 8 + i],  vb[(size_t)irow[rr*33 + 8 + i]  * DHEAD + lane2], a1);
            a2 = fmaf(wrow[rr*33 + 16 + i], vb[(size_t)irow[rr*33 + 16 + i] * DHEAD + lane2], a2);
            a3 = fmaf(wrow[rr*33 + 24 + i], vb[(size_t)irow[rr*33 + 24 + i] * DHEAD + lane2], a3);
        }
        float accv = (a0 + a1) + (a2 + a3);
        size_t oi = ((size_t)(b * T_SEQ + t0 + rr)) * DMODEL + h * DHEAD + lane2;
        float s16 = 16.f * accv;
        _Float16 hh = (_Float16)s16;
        outH[oi] = hh;
        outL[oi] = (_Float16)(s16 - (float)hh);
    }
}

// ---------------------------------------------------------------------------
// LayerNorm (+residual); also emits x16 f16 hi/lo planes of the output
// ---------------------------------------------------------------------------
__global__ __launch_bounds__(256) void ln_k(
    const float* __restrict__ x, const float* __restrict__ res,
    const float* __restrict__ g, const float* __restrict__ bb,
    float* __restrict__ out, _Float16* __restrict__ oH, _Float16* __restrict__ oL)
{
    __shared__ float red[8];
    const int row = blockIdx.x;
    const int tid = threadIdx.x;
    const float* xr = x + (size_t)row * DMODEL;
    float v0 = xr[tid], v1 = xr[tid + 256];
    if (res) {
        const float* rr = res + (size_t)row * DMODEL;
        v0 += rr[tid]; v1 += rr[tid + 256];
    }
    float s = v0 + v1;
    #pragma unroll
    for (int o = 1; o < 64; o <<= 1) s += __shfl_xor(s, o);
    const int wid = tid >> 6, lane = tid & 63;
    if (lane == 0) red[wid] = s;
    __syncthreads();
    float mean = (red[0] + red[1] + red[2] + red[3]) * (1.f / DMODEL);
    float d0 = v0 - mean, d1 = v1 - mean;
    float qs = d0*d0 + d1*d1;
    #pragma unroll
    for (int o = 1; o < 64; o <<= 1) qs += __shfl_xor(qs, o);
    if (lane == 0) red[4 + wid] = qs;
    __syncthreads();
    float var = (red[4] + red[5] + red[6] + red[7]) * (1.f / DMODEL);
    float rs = rsqrtf(var + 1e-5f);
    float o0 = d0 * rs * g[tid]       + bb[tid];
    float o1 = d1 * rs * g[tid + 256] + bb[tid + 256];
    size_t base = (size_t)row * DMODEL;
    out[base + tid]       = o0;
    out[base + tid + 256] = o1;
    float s0 = 16.f * o0, s1 = 16.f * o1;
    _Float16 h0 = (_Float16)s0, h1 = (_Float16)s1;
    oH[base + tid]       = h0;
    oH[base + tid + 256] = h1;
    oL[base + tid]       = (_Float16)(s0 - (float)h0);
    oL[base + tid + 256] = (_Float16)(s1 - (float)h1);
}

// ---------------------------------------------------------------------------
__global__ __launch_bounds__(256) void pool_k(
    const float* __restrict__ h, float* __restrict__ part)
{
    const int chunk = blockIdx.x & 15;
    const int idx = (blockIdx.x >> 4) * 256 + threadIdx.x;
    const int b = idx >> 9, d = idx & 511;
    const float* p = h + ((size_t)b * T_SEQ + chunk * 128) * DMODEL + d;
    float s = 0.f;
    for (int t = 0; t < 128; ++t) s += p[(size_t)t * DMODEL];
    part[chunk * 1024 + idx] = s;
}

__global__ __launch_bounds__(256) void poolsum_k(
    const float* __restrict__ part, float* __restrict__ pooled)
{
    int idx = blockIdx.x * 256 + threadIdx.x;
    float s = 0.f;
    #pragma unroll
    for (int c = 0; c < 16; ++c) s += part[c * 1024 + idx];
    pooled[idx] = s * (1.f / T_SEQ);
}

__global__ __launch_bounds__(256) void cls_k(
    const float* __restrict__ pooled, const float* __restrict__ w,
    const float* __restrict__ bias, float* __restrict__ out)
{
    const int wid = threadIdx.x >> 6, lane = threadIdx.x & 63;
    const int oi = blockIdx.x * 4 + wid;
    const int b = oi >> 8, o = oi & 255;
    const float* pr = pooled + b * DMODEL;
    const float* wr = w + (size_t)o * DMODEL;
    float s = 0.f;
    for (int d = lane; d < DMODEL; d += 64) s = fmaf(pr[d], wr[d], s);
    #pragma unroll
    for (int off = 1; off < 64; off <<= 1) s += __shfl_xor(s, off);
    if (lane == 0) out[oi] = s + bias[o];
}

// ---------------------------------------------------------------------------
extern "C" void kernel_launch(void* const* d_in, const int* in_sizes, int n_in,
                              void* d_out, int out_size, void* d_ws, size_t ws_size,
                              hipStream_t stream)
{
    const float* x     = (const float*)d_in[0];
    const float* emb_w = (const float*)d_in[1];
    const float* emb_b = (const float*)d_in[2];
    const float* pos   = (const float*)d_in[3];
    const float* wq    = (const float*)d_in[4];
    const float* bq    = (const float*)d_in[5];
    const float* wk    = (const float*)d_in[6];
    const float* bk    = (const float*)d_in[7];
    const float* wv    = (const float*)d_in[8];
    const float* bv    = (const float*)d_in[9];
    const float* wo    = (const float*)d_in[10];
    const float* bo    = (const float*)d_in[11];
    const float* ln1g  = (const float*)d_in[12];
    const float* ln1b  = (const float*)d_in[13];
    const float* fc1w  = (const float*)d_in[14];
    const float* fc1b  = (const float*)d_in[15];
    const float* fc2w  = (const float*)d_in[16];
    const float* fc2b  = (const float*)d_in[17];
    const float* ln2g  = (const float*)d_in[18];
    const float* ln2b  = (const float*)d_in[19];
    const float* fng   = (const float*)d_in[20];
    const float* fnb   = (const float*)d_in[21];
    const float* clsw  = (const float*)d_in[22];
    const float* clsb  = (const float*)d_in[23];

    float* ws = (float*)d_ws;
    const size_t SZ  = (size_t)MROWS * DMODEL;   // 2,097,152 floats
    const size_t HP  = SZ / 2;
    float*     h     = ws;
    float*     t1    = ws + 1*SZ;
    _Float16*  hH    = (_Float16*)(ws + 2*SZ);
    _Float16*  hL    = (_Float16*)(ws + 2*SZ + HP);
    _Float16*  aoH   = (_Float16*)(ws + 3*SZ);
    _Float16*  aoL   = (_Float16*)(ws + 3*SZ + HP);
    _Float16*  qbH   = (_Float16*)(ws + 4*SZ);
    _Float16*  qbL   = (_Float16*)(ws + 4*SZ + HP);
    _Float16*  kbH   = (_Float16*)(ws + 5*SZ);
    _Float16*  kbL   = (_Float16*)(ws + 5*SZ + HP);
    float*     vbuf  = ws + 6*SZ;
    _Float16*  WcatH = (_Float16*)(ws + 7*SZ);
    _Float16*  WcatL = (_Float16*)(ws + 7*SZ + 393216);
    _Float16*  WoH   = (_Float16*)(ws + 7*SZ + 786432);
    _Float16*  WoL   = (_Float16*)(ws + 7*SZ + 917504);
    _Float16*  W1H   = (_Float16*)(ws + 7*SZ + 1048576);
    _Float16*  W1L   = (_Float16*)(ws + 7*SZ + 1572864);
    _Float16*  W2H   = (_Float16*)(ws + 7*SZ + 2097152);
    _Float16*  W2L   = (_Float16*)(ws + 7*SZ + 2621440);
    float*     bcat  = ws + 7*SZ + 3145728;
    float*     pooled= ws + 7*SZ + 3145728 + 1536;
    float*     part  = ws + 7*SZ + 3145728 + 1536 + 1024;
    _Float16*  hid   = (_Float16*)(ws + 4*SZ);   // aliases q/k planes (dead then)
    const size_t needed = (7*SZ + 3145728 + 1536 + 1024 + 16384) * sizeof(float);
    if (ws_size < needed) return;

    dim3 blk(256);

    // embedding GEMM with fused h-split epilogue (replaces gemm_k + cvtw_k)
    gemm2_k<<<dim3(DMODEL/64, MROWS/128), blk, 0, stream>>>(
        x, emb_w, emb_b, pos, h, hH, hL, MROWS, DMODEL, 128);

    for (int l = 0; l < NLAYER; ++l) {
        const float* wq_l = wq + (size_t)l*DMODEL*DMODEL;
        const float* bq_l = bq + (size_t)l*DMODEL;
        const float* wk_l = wk + (size_t)l*DMODEL*DMODEL;
        const float* bk_l = bk + (size_t)l*DMODEL;
        const float* wv_l = wv + (size_t)l*DMODEL*DMODEL;
        const float* bv_l = bv + (size_t)l*DMODEL;
        const float* wo_l = wo + (size_t)l*DMODEL*DMODEL;
        const float* bo_l = bo + (size_t)l*DMODEL;
        const float* f1w_l = fc1w + (size_t)l*FDIM*DMODEL;
        const float* f1b_l = fc1b + (size_t)l*FDIM;
        const float* f2w_l = fc2w + (size_t)l*DMODEL*FDIM;
        const float* f2b_l = fc2b + (size_t)l*DMODEL;

        cvtlayer_k<<<dim3(12294), blk, 0, stream>>>(
            wq_l, wk_l, wv_l, bq_l, bk_l, bv_l, wo_l, f1w_l, f2w_l,
            WcatH, WcatL, bcat, WoH, WoL, W1H, W1L, W2H, W2L);

        mgemm_k<64,128,0,0,2,6><<<dim3(768), dim3(512), 0, stream>>>(
            hH, hL, WcatH, WcatL, bcat,
            (float*)qbH, (float*)qbL, (float*)kbH, (float*)kbL, vbuf,
            MROWS, 1536, DMODEL);

        attn_k<<<dim3(T_SEQ/64, NB*NHEAD), dim3(512), 0, stream>>>(
            qbH, qbL, kbH, kbL, vbuf, aoH, aoL);

        mgemm_k<64,64,0,2,0,4><<<dim3(512), dim3(512), 0, stream>>>(
            aoH, aoL, WoH, WoL, bo_l, t1, nullptr, nullptr, nullptr, nullptr,
            MROWS, DMODEL, DMODEL);
        ln_k<<<dim3(MROWS), blk, 0, stream>>>(h, t1, ln1g + (size_t)l*DMODEL,
                                              ln1b + (size_t)l*DMODEL, h, hH, hL);

        mgemm_k<128,128,0,3,0,4><<<dim3(512), dim3(512), 0, stream>>>(
            hH, hL, W1H, W1L, f1b_l, (float*)hid, nullptr, nullptr, nullptr, nullptr,
            MROWS, FDIM, DMODEL);
        mgemm_k<64,64,1,2,0,4><<<dim3(512), dim3(512), 0, stream>>>(
            hid, nullptr, W2H, W2L, f2b_l, t1, nullptr, nullptr, nullptr, nullptr,
            MROWS, DMODEL, FDIM);
        ln_k<<<dim3(MROWS), blk, 0, stream>>>(h, t1, ln2g + (size_t)l*DMODEL,
                                              ln2b + (size_t)l*DMODEL, h, hH, hL);
    }

    ln_k<<<dim3(MROWS), blk, 0, stream>>>(h, nullptr, fng, fnb, h, hH, hL);
    pool_k<<<dim3(64), blk, 0, stream>>>(h, part);
    poolsum_k<<<dim3(4), blk, 0, stream>>>(part, pooled);
    cls_k<<<dim3(128), blk, 0, stream>>>(pooled, clsw, clsb, (float*)d_out);
}